// Round 13
// baseline (322.977 us; speedup 1.0000x reference)
//
#include <hip/hip_runtime.h>

// Kalman filter, BATCH=256, SEQ=4096, N=16, M=8, U=4.
// Riccati gain converges -> 8 exact steps then frozen steady gain. Chunked
// parallel scan over x' = G x + K z + Bf u, 32-step chunks:
//   k_riccati: 8 exact steps, steady mats, G-powers G^1..G^32 (HI=G^32).
//   k_phase1:  chunk j zero-response from 0 (chunk 0: true traj from x0),
//              WRITES response y_t to out, and d_j to the DB slot.
//   k_scan:    serial chunk-level scan xs_{j+1} = H xs_j + d_j (R1 ring).
//   k_corr:    out[t] += G^{t-s0} xs_j for chunks 1..127 -- replaces the
//              old phase3 recurrence replay with a dependency-free
//              streaming RMW (affine identity x_t = y_t + G^{t-s0} xs_j).
// Evidence ledger: R1 scan ring 220->195.6 WIN. Register-prefetch ladder
// DEAD (R3 -70%, R7 neutral, R9 -90%): compiler re-serializes source-level
// depth (guide common-mistake #5). R10 fat blocks -10us. R11 LDS-staging
// neutral: recurrence step costs ~1000+cy regardless of operand feed ->
// any kernel RUNNING the recurrence costs ~45us. R12/R13: run it ONCE
// (phase1), turn the second pass into a scan-style affine correction with
// no serial chain -> BW-bound ~21-30us instead of 47.
// (R13 == R12 resubmitted: R12 hit a GPU-acquisition timeout, never ran.)
// Phases: 4 lanes/batch, x broadcast via DPP quad-perm, matrices in VGPRs.

#define SEQ_T  4096
#define NSTEP  4095
#define NB     256
#define NEX    8
#define LCH    32
#define NCHT   128   // chunks 0..127; chunk j covers steps j*32 .. j*32+31 (<4095)

// workspace layout (float offsets); slot j of DB holds d_j, overwritten by
// k_scan with xs_{j+1} (start state of chunk j+1). slot 0 stays d_0 = xs_1.
#define EX_OFF 0
#define ST_OFF (NEX*448)
#define HI_OFF (ST_OFF+448)
#define DB_OFF (HI_OFF+256)
#define GP_OFF (DB_OFF + NCHT*(NB*16))   // G^1..G^32: 32 x 256 floats
// total = 4288 + 524288 + 8192 = 536,768 floats ~ 2.15 MB

// ---------------------------------------------------------------- DPP util
template<int KQ>
__device__ __forceinline__ void bc4(const float* xr, float* xk) {
#pragma unroll
  for (int r = 0; r < 4; r++)
    xk[r] = __int_as_float(__builtin_amdgcn_update_dpp(
        0, __float_as_int(xr[r]), KQ * 0x55, 0xF, 0xF, true));
}

// ---------------------------------------------------------------- k_riccati
__global__ __launch_bounds__(64) void k_riccati(
    const float* __restrict__ Ag, const float* __restrict__ Bg,
    const float* __restrict__ Cg, const float* __restrict__ Qg,
    const float* __restrict__ Rg, float* __restrict__ ws)
{
  const int l = threadIdx.x;
  __shared__ float As[256], Qs[256], Cs[128], Bs[64], CA[128], CB[32];
  __shared__ float Pp[256], Vv[128], Km[128], Gm[256], T1[256], T2[256], Xs[64];

#pragma unroll
  for (int j=0;j<4;j++){ int e=l+64*j; As[e]=Ag[e]; Qs[e]=Qg[e]; }
  Cs[l]=Cg[l]; Cs[l+64]=Cg[l+64];
  Bs[l]=Bg[l];
  const float rr = Rg[l];
  __syncthreads();

  const int r4=l>>2, g4=l&3;   // (row, col-group) for 16x16 work
  const int r8=l>>3, c8=l&7;   // (row, col) for 8-wide work

  // CA = C*A (8x16), CB = C*B (8x4), Pp0 = A*A^T + Q
  { int e=l; { int r=e>>4,c=e&15; float a=0.f;
      for (int k=0;k<16;k++) a+=Cs[r*16+k]*As[k*16+c]; CA[e]=a; }
    e=l+64; { int r=e>>4,c=e&15; float a=0.f;
      for (int k=0;k<16;k++) a+=Cs[r*16+k]*As[k*16+c]; CA[e]=a; }
    if (l<32){ int r=l>>2,c=l&3; float a=0.f;
      for (int k=0;k<16;k++) a+=Cs[r*16+k]*Bs[k*4+c]; CB[l]=a; }
#pragma unroll
    for (int j=0;j<4;j++){ int c=4*g4+j; float a=Qs[r4*16+c];
      for (int k=0;k<16;k++) a+=As[r4*16+k]*As[c*16+k]; Pp[r4*16+c]=a; }
  }
  __syncthreads();

  float kv0=0.f, kv1=0.f, bfv=0.f;
  for (int s=0;s<NEX;s++){
    // V = P_pri * C^T (16x8), 2 elems/lane
    { int e=l; { int r=e>>3,c=e&7; float a=0.f;
        for (int k=0;k<16;k++) a+=Pp[r*16+k]*Cs[c*16+k]; Vv[e]=a; }
      e=l+64; { int r=e>>3,c=e&7; float a=0.f;
        for (int k=0;k<16;k++) a+=Pp[r*16+k]*Cs[c*16+k]; Vv[e]=a; } }
    __syncthreads();
    // S = C*V + R, then in-register Gauss-Jordan via shfl (no barriers)
    { float sv=rr;
      for (int k=0;k<16;k++) sv += Cs[r8*16+k]*Vv[k*8+c8];
      float xv = (r8==c8)?1.f:0.f;
#pragma unroll
      for (int p=0;p<8;p++){
        float spp = __shfl(sv, p*9);
        float pr  = 1.0f/spp;
        float spc = __shfl(sv, p*8+c8);
        float xpc = __shfl(xv, p*8+c8);
        float srp = __shfl(sv, r8*8+p);
        float f = srp*pr;
        if (r8==p){ sv = spc*pr; xv = xpc*pr; }
        else      { sv -= f*spc; xv -= f*xpc; }
      }
      Xs[l]=xv; }
    __syncthreads();
    // K = V * S^-1 (16x8), 2 elems/lane; keep in regs for emit
    { int e=l; { int r=e>>3,c=e&7; float a=0.f;
        for (int k=0;k<8;k++) a+=Vv[r*8+k]*Xs[k*8+c]; kv0=a; Km[e]=a; }
      e=l+64; { int r=e>>3,c=e&7; float a=0.f;
        for (int k=0;k<8;k++) a+=Vv[r*8+k]*Xs[k*8+c]; kv1=a; Km[e]=a; } }
    __syncthreads();
    // G = A - K*CA ; W = P - K*V^T (in place over Pp) ; Bf = B - K*CB ; emit
    { float gv[4];
#pragma unroll
      for (int j=0;j<4;j++){ int c=4*g4+j;
        float a=As[r4*16+c], w=Pp[r4*16+c];
        for (int k=0;k<8;k++){ a -= Km[r4*8+k]*CA[k*16+c]; w -= Km[r4*8+k]*Vv[c*8+k]; }
        gv[j]=a; Gm[r4*16+c]=a; Pp[r4*16+c]=w; }
      bfv = Bs[l];
      for (int k=0;k<8;k++) bfv -= Km[r4*8+k]*CB[k*4+g4];
      float* dst = ws + EX_OFF + s*448;
      *reinterpret_cast<float4*>(dst + r4*16 + g4*4) =
          make_float4(gv[0],gv[1],gv[2],gv[3]);
      dst[256+l]=kv0; dst[256+64+l]=kv1; dst[384+l]=bfv;
    }
    __syncthreads();
    // T1 = A * W
#pragma unroll
    for (int j=0;j<4;j++){ int c=4*g4+j; float a=0.f;
      for (int k=0;k<16;k++) a+=As[r4*16+k]*Pp[k*16+c]; T1[r4*16+c]=a; }
    __syncthreads();
    // P_pri' = T1 * A^T + Q
#pragma unroll
    for (int j=0;j<4;j++){ int c=4*g4+j; float a=Qs[r4*16+c];
      for (int k=0;k<16;k++) a+=T1[r4*16+k]*As[c*16+k]; Pp[r4*16+c]=a; }
    __syncthreads();
  }
  // steady mats = last step's (converged)
  { float* dst = ws + ST_OFF;
    *reinterpret_cast<float4*>(dst + r4*16 + g4*4) =
        *reinterpret_cast<float4*>(&Gm[r4*16 + g4*4]);
    dst[256+l]=kv0; dst[256+64+l]=kv1; dst[384+l]=bfv; }
  // G-powers: GP[it] = G^{it+1} for it=0..31; HI = G^32 (scan uses it).
#pragma unroll
  for (int j=0;j<4;j++) T1[l+64*j]=Gm[l+64*j];
  __syncthreads();
  for (int it=0; it<32; it++){
#pragma unroll
    for (int j=0;j<4;j++) ws[GP_OFF + it*256 + l+64*j] = T1[l+64*j];
    if (it==31){
#pragma unroll
      for (int j=0;j<4;j++) ws[HI_OFF + l+64*j] = T1[l+64*j];
      break;
    }
#pragma unroll
    for (int j=0;j<4;j++){ int c=4*g4+j; float a=0.f;
      for (int k=0;k<16;k++) a+=T1[r4*16+k]*Gm[k*16+c]; T2[r4*16+c]=a; }
    __syncthreads();
#pragma unroll
    for (int j=0;j<4;j++) T1[l+64*j]=T2[l+64*j];
    __syncthreads();
  }
}

// ---------------------------------------------------------- phase mat load
__device__ __forceinline__ void ld_rows(const float* __restrict__ m, int q,
    float gm[4][16], float km[4][8], float bf[4][4]) {
#pragma unroll
  for (int r=0;r<4;r++){
    const int row = 4*q + r;
    const float4* gp = reinterpret_cast<const float4*>(m + row*16);
#pragma unroll
    for (int kk=0;kk<4;kk++){ float4 t=gp[kk];
      gm[r][4*kk]=t.x; gm[r][4*kk+1]=t.y; gm[r][4*kk+2]=t.z; gm[r][4*kk+3]=t.w; }
    const float4* kp = reinterpret_cast<const float4*>(m + 256 + row*8);
#pragma unroll
    for (int kk=0;kk<2;kk++){ float4 t=kp[kk];
      km[r][4*kk]=t.x; km[r][4*kk+1]=t.y; km[r][4*kk+2]=t.z; km[r][4*kk+3]=t.w; }
    float4 t = *reinterpret_cast<const float4*>(m + 384 + row*4);
    bf[r][0]=t.x; bf[r][1]=t.y; bf[r][2]=t.z; bf[r][3]=t.w;
  }
}

// MODE 0: phase1 steady chunk (zero-response; writes y_t to out + d_j)
// MODE 1: phase1 chunk 0 (exact+steady from x0, writes out t=0..32 and d_0)
// Inner loop: R7 body (branch-free depth-2 named rotation, single basic
// block) — proven neutral-best; do not touch (R3/R9 lessons).
template<int MODE>
__device__ __forceinline__ void chunk_run(
    const float* __restrict__ obs, const float* __restrict__ inp,
    const float* __restrict__ x0g, float* __restrict__ ws,
    float* __restrict__ out, int j, int g)
{
  const int l=threadIdx.x, bl=l>>2, q=l&3, b=g*16+bl;
  const int s0 = j*LCH;
  const int nst = (NSTEP - s0 < LCH) ? (NSTEP - s0) : LCH;

  float gm[4][16], km[4][8], bf[4][4];
  if (MODE==1) ld_rows(ws + EX_OFF, q, gm, km, bf);
  else         ld_rows(ws + ST_OFF, q, gm, km, bf);

  float xr[4];
  if (MODE==0){ xr[0]=xr[1]=xr[2]=xr[3]=0.f; }
  else {
    float4 x = *reinterpret_cast<const float4*>(x0g + q*4);
    xr[0]=x.x; xr[1]=x.y; xr[2]=x.z; xr[3]=x.w;
    *reinterpret_cast<float4*>(out + (size_t)b*(SEQ_T*16) + q*4) = x;  // t=0
  }

  const float* zp = obs + (size_t)b*(SEQ_T*8);
  const float* up = inp + (size_t)b*(SEQ_T*4);

  // depth-2 branch-free prefetch with NAMED rotating registers.
  float4 z0a = *reinterpret_cast<const float4*>(zp + (size_t)(s0+1)*8);
  float4 z1a = *reinterpret_cast<const float4*>(zp + (size_t)(s0+1)*8 + 4);
  float4 u0a = *reinterpret_cast<const float4*>(up + (size_t)(s0+1)*4);
  float4 z0b = *reinterpret_cast<const float4*>(zp + (size_t)(s0+2)*8);
  float4 z1b = *reinterpret_cast<const float4*>(zp + (size_t)(s0+2)*8 + 4);
  float4 u0b = *reinterpret_cast<const float4*>(up + (size_t)(s0+2)*4);

  for (int st=0; st<nst; st++){
    float4 z0=z0a, z1=z1a, u0=u0a;
    z0a=z0b; z1a=z1b; u0a=u0b;
    { int tn = s0+st+3; tn = (tn > NSTEP) ? NSTEP : tn;
      const size_t t = (size_t)tn;
      z0b = *reinterpret_cast<const float4*>(zp + t*8);
      z1b = *reinterpret_cast<const float4*>(zp + t*8 + 4);
      u0b = *reinterpret_cast<const float4*>(up + t*4);
    }
    float xk[16];
    bc4<0>(xr, xk); bc4<1>(xr, xk+4); bc4<2>(xr, xk+8); bc4<3>(xr, xk+12);
    float xn[4];
#pragma unroll
    for (int r=0;r<4;r++){
      float a = bf[r][0]*u0.x + bf[r][1]*u0.y + bf[r][2]*u0.z + bf[r][3]*u0.w;
      a += km[r][0]*z0.x + km[r][1]*z0.y + km[r][2]*z0.z + km[r][3]*z0.w;
      a += km[r][4]*z1.x + km[r][5]*z1.y + km[r][6]*z1.z + km[r][7]*z1.w;
#pragma unroll
      for (int k=0;k<16;k++) a += gm[r][k]*xk[k];
      xn[r]=a;
    }
#pragma unroll
    for (int r=0;r<4;r++) xr[r]=xn[r];
    // write y_t (MODE 0) / x_t (MODE 1) -- k_corr adds G^i xs_j later.
    *reinterpret_cast<float4*>(out + (size_t)b*(SEQ_T*16) +
                               (size_t)(s0+st+1)*16 + q*4) =
        make_float4(xr[0],xr[1],xr[2],xr[3]);
    if (MODE==1 && st+1 < nst){
      if (st+1 < NEX)       ld_rows(ws + EX_OFF + (st+1)*448, q, gm, km, bf);
      else if (st+1 == NEX) ld_rows(ws + ST_OFF, q, gm, km, bf);
    }
  }
  *reinterpret_cast<float4*>(ws + DB_OFF + (size_t)j*(NB*16) + b*16 + q*4) =
      make_float4(xr[0],xr[1],xr[2],xr[3]);
}

__global__ __launch_bounds__(64,2) void k_phase1(
    const float* __restrict__ obs, const float* __restrict__ inp,
    const float* __restrict__ x0g, float* __restrict__ ws,
    float* __restrict__ out)
{
  const int j = blockIdx.x>>4, g = blockIdx.x&15;
  if (j==0) chunk_run<1>(obs, inp, x0g, ws, out, j, g);
  else      chunk_run<0>(obs, inp, x0g, ws, out, j, g);
}

// ------------------------------------------------------------- k_corr
// out[s0+1+i] += G^{i+1} xs_j for chunks j=1..127. No recurrence: steps
// are independent, loads pipeline under FMAs, BW-bound streaming RMW.
// G-powers are 32KB shared by all blocks -> L2-resident after first touch.
__global__ __launch_bounds__(64,2) void k_corr(
    float* __restrict__ ws, float* __restrict__ out)
{
  const int j = 1 + (blockIdx.x>>4), g = blockIdx.x&15;
  const int l = threadIdx.x, bl=l>>2, q=l&3, b=g*16+bl;
  const int s0 = j*LCH;
  const int nst = (NSTEP - s0 < LCH) ? (NSTEP - s0) : LCH;

  // xs_j -> full 16-vector via quad broadcast (once per chunk)
  float xr[4];
  { float4 x = *reinterpret_cast<const float4*>(
      ws + DB_OFF + (size_t)(j-1)*(NB*16) + b*16 + q*4);
    xr[0]=x.x; xr[1]=x.y; xr[2]=x.z; xr[3]=x.w; }
  float xk[16];
  bc4<0>(xr, xk); bc4<1>(xr, xk+4); bc4<2>(xr, xk+8); bc4<3>(xr, xk+12);

  float* yp = out + (size_t)b*(SEQ_T*16) + (size_t)(s0+1)*16 + q*4;
  const float* gpw = ws + GP_OFF + q*64;   // rows 4q..4q+3 of each power

  for (int i=0; i<nst; i++){
    const float* pm = gpw + i*256;
    float4 y = *reinterpret_cast<const float4*>(yp + (size_t)i*16);
    float xn[4];
#pragma unroll
    for (int r=0;r<4;r++){
      const float4* pr = reinterpret_cast<const float4*>(pm + r*16);
      float4 p0=pr[0], p1=pr[1], p2=pr[2], p3=pr[3];
      xn[r] = p0.x*xk[0]+p0.y*xk[1]+p0.z*xk[2]+p0.w*xk[3]
            + p1.x*xk[4]+p1.y*xk[5]+p1.z*xk[6]+p1.w*xk[7]
            + p2.x*xk[8]+p2.y*xk[9]+p2.z*xk[10]+p2.w*xk[11]
            + p3.x*xk[12]+p3.y*xk[13]+p3.z*xk[14]+p3.w*xk[15];
    }
    *reinterpret_cast<float4*>(yp + (size_t)i*16) =
        make_float4(y.x+xn[0], y.y+xn[1], y.z+xn[2], y.w+xn[3]);
  }
}

// ------------------------------------------------------------- k_scan
// Serial chunk-level scan, 126 dependent steps. 14-deep statically-indexed
// register ring (126 = 9*14) keeps 14 loads in flight. All ring indices
// are compile-time constants.
__global__ __launch_bounds__(256) void k_scan(float* __restrict__ ws)
{
  const int tid=threadIdx.x, lane=tid&63, wv=tid>>6, bl=lane>>2, q=lane&3;
  const int b = blockIdx.x*64 + wv*16 + bl;
  float hm[4][16];
#pragma unroll
  for (int r=0;r<4;r++){
    const int row = 4*q + r;
    const float4* hp = reinterpret_cast<const float4*>(ws + HI_OFF + row*16);
#pragma unroll
    for (int kk=0;kk<4;kk++){ float4 t=hp[kk];
      hm[r][4*kk]=t.x; hm[r][4*kk+1]=t.y; hm[r][4*kk+2]=t.z; hm[r][4*kk+3]=t.w; }
  }
  float* p = ws + DB_OFF + (size_t)b*16 + q*4;   // slot stride = NB*16 floats
  float4 xi = *reinterpret_cast<const float4*>(p);   // slot 0 = d_0 = xs_1
  float xr[4]={xi.x,xi.y,xi.z,xi.w};

  float4 dbuf[14];
#pragma unroll
  for (int k=0;k<14;k++)
    dbuf[k] = *reinterpret_cast<const float4*>(p + (size_t)(1+k)*(NB*16));

  for (int base=0; base<9; base++){
#pragma unroll
    for (int k=0;k<14;k++){
      const int jj = 1 + base*14 + k;           // 1..126
      float4 d = dbuf[k];
      if (jj+14 <= 126)                          // refill ring 14 ahead
        dbuf[k] = *reinterpret_cast<const float4*>(
            p + (size_t)(jj+14)*(NB*16));
      float xk[16];
      bc4<0>(xr, xk); bc4<1>(xr, xk+4); bc4<2>(xr, xk+8); bc4<3>(xr, xk+12);
      float xn[4]={d.x,d.y,d.z,d.w};
#pragma unroll
      for (int r=0;r<4;r++){
#pragma unroll
        for (int kk=0;kk<16;kk++) xn[r]+=hm[r][kk]*xk[kk];
      }
#pragma unroll
      for (int r=0;r<4;r++) xr[r]=xn[r];
      *reinterpret_cast<float4*>(p + (size_t)jj*(NB*16)) =
          make_float4(xr[0],xr[1],xr[2],xr[3]);   // slot jj := xs_{jj+1}
    }
  }
}

// ------------------------------------------------------------- launcher
extern "C" void kernel_launch(void* const* d_in, const int* in_sizes, int n_in,
                              void* d_out, int out_size, void* d_ws, size_t ws_size,
                              hipStream_t stream) {
  const float* obs = (const float*)d_in[0];
  const float* inp = (const float*)d_in[1];
  const float* A   = (const float*)d_in[2];
  const float* B   = (const float*)d_in[3];
  const float* C   = (const float*)d_in[4];
  const float* Q   = (const float*)d_in[5];
  const float* R   = (const float*)d_in[6];
  const float* x0  = (const float*)d_in[7];
  float* out = (float*)d_out;
  float* ws  = (float*)d_ws;

  k_riccati<<<dim3(1),        dim3(64),  0, stream>>>(A, B, C, Q, R, ws);
  k_phase1 <<<dim3(NCHT*16),  dim3(64),  0, stream>>>(obs, inp, x0, ws, out);
  k_scan   <<<dim3(4),        dim3(256), 0, stream>>>(ws);
  k_corr   <<<dim3(127*16),   dim3(64),  0, stream>>>(ws, out);
}

// Round 14
// 165.269 us; speedup vs baseline: 1.9543x; 1.9543x over previous
//
#include <hip/hip_runtime.h>

// Kalman filter, BATCH=256, SEQ=4096, N=16, M=8, U=4.
// R14 STRUCTURE: warm-up replaces the parallel scan entirely.
// Physics: G = (I-KC)A has rho ~ 0.45 (Riccati contraction ~0.2 = rho^2),
// so G^24 ~ 5e-9 -- state information older than 24 steps is numerically
// irrelevant vs the 7.8e-3 tolerance and the already-accepted steady-gain
// approximation. Each chunk j>=1 starts the recurrence from state 0 at
// t = s0-24 (24 discarded warm-up steps, steady gains), then runs its 32
// real steps writing out. Chunk 0 runs exact from x0 (EX gains first 8).
// DELETED: k_scan, k_phase3/k_corr, d_j buffer, H=G^32, G-powers.
// Two kernels total: k_riccati + k_chunk.
// Evidence ledger: R1 scan-ring 220->195.6 WIN. Register-prefetch ladder
// DEAD (R3 -70%, R7 neutral, R9 -90%): compiler re-serializes source-level
// depth. R10 fat blocks -10us. R11 LDS-staging neutral: the 32-step
// recurrence kernel costs ~45us regardless of operand feed. R13 k_corr RMW
// 138us (worse than the recurrence it replaced). So: run the recurrence
// ONCE (1.75x steps) instead of twice + scan: ~107us kernel time -> ~80us.
// Inner loop: R7 body (branch-free depth-2 named rotation, single basic
// block) -- proven neutral-best; do not touch (R3/R9 lessons).

#define SEQ_T  4096
#define NSTEP  4095
#define NB     256
#define NEX    8
#define LCH    32
#define NCHT   128   // chunks 0..127; chunk j covers steps j*32 .. j*32+31 (<4095)
#define WUP    24    // warm-up steps; G^24 ~ 5e-9 (rho ~ 0.45)

// workspace layout (float offsets): EX gains (8 steps x 448) + ST gains.
#define EX_OFF 0
#define ST_OFF (NEX*448)
// total = 8*448 + 448 = 4032+448 floats (~18 KB)

// ---------------------------------------------------------------- DPP util
template<int KQ>
__device__ __forceinline__ void bc4(const float* xr, float* xk) {
#pragma unroll
  for (int r = 0; r < 4; r++)
    xk[r] = __int_as_float(__builtin_amdgcn_update_dpp(
        0, __float_as_int(xr[r]), KQ * 0x55, 0xF, 0xF, true));
}

// ---------------------------------------------------------------- k_riccati
__global__ __launch_bounds__(64) void k_riccati(
    const float* __restrict__ Ag, const float* __restrict__ Bg,
    const float* __restrict__ Cg, const float* __restrict__ Qg,
    const float* __restrict__ Rg, float* __restrict__ ws)
{
  const int l = threadIdx.x;
  __shared__ float As[256], Qs[256], Cs[128], Bs[64], CA[128], CB[32];
  __shared__ float Pp[256], Vv[128], Km[128], Gm[256], T1[256], Xs[64];

#pragma unroll
  for (int j=0;j<4;j++){ int e=l+64*j; As[e]=Ag[e]; Qs[e]=Qg[e]; }
  Cs[l]=Cg[l]; Cs[l+64]=Cg[l+64];
  Bs[l]=Bg[l];
  const float rr = Rg[l];
  __syncthreads();

  const int r4=l>>2, g4=l&3;   // (row, col-group) for 16x16 work
  const int r8=l>>3, c8=l&7;   // (row, col) for 8-wide work

  // CA = C*A (8x16), CB = C*B (8x4), Pp0 = A*A^T + Q
  { int e=l; { int r=e>>4,c=e&15; float a=0.f;
      for (int k=0;k<16;k++) a+=Cs[r*16+k]*As[k*16+c]; CA[e]=a; }
    e=l+64; { int r=e>>4,c=e&15; float a=0.f;
      for (int k=0;k<16;k++) a+=Cs[r*16+k]*As[k*16+c]; CA[e]=a; }
    if (l<32){ int r=l>>2,c=l&3; float a=0.f;
      for (int k=0;k<16;k++) a+=Cs[r*16+k]*Bs[k*4+c]; CB[l]=a; }
#pragma unroll
    for (int j=0;j<4;j++){ int c=4*g4+j; float a=Qs[r4*16+c];
      for (int k=0;k<16;k++) a+=As[r4*16+k]*As[c*16+k]; Pp[r4*16+c]=a; }
  }
  __syncthreads();

  float kv0=0.f, kv1=0.f, bfv=0.f;
  for (int s=0;s<NEX;s++){
    // V = P_pri * C^T (16x8), 2 elems/lane
    { int e=l; { int r=e>>3,c=e&7; float a=0.f;
        for (int k=0;k<16;k++) a+=Pp[r*16+k]*Cs[c*16+k]; Vv[e]=a; }
      e=l+64; { int r=e>>3,c=e&7; float a=0.f;
        for (int k=0;k<16;k++) a+=Pp[r*16+k]*Cs[c*16+k]; Vv[e]=a; } }
    __syncthreads();
    // S = C*V + R, then in-register Gauss-Jordan via shfl (no barriers)
    { float sv=rr;
      for (int k=0;k<16;k++) sv += Cs[r8*16+k]*Vv[k*8+c8];
      float xv = (r8==c8)?1.f:0.f;
#pragma unroll
      for (int p=0;p<8;p++){
        float spp = __shfl(sv, p*9);
        float pr  = 1.0f/spp;
        float spc = __shfl(sv, p*8+c8);
        float xpc = __shfl(xv, p*8+c8);
        float srp = __shfl(sv, r8*8+p);
        float f = srp*pr;
        if (r8==p){ sv = spc*pr; xv = xpc*pr; }
        else      { sv -= f*spc; xv -= f*xpc; }
      }
      Xs[l]=xv; }
    __syncthreads();
    // K = V * S^-1 (16x8), 2 elems/lane; keep in regs for emit
    { int e=l; { int r=e>>3,c=e&7; float a=0.f;
        for (int k=0;k<8;k++) a+=Vv[r*8+k]*Xs[k*8+c]; kv0=a; Km[e]=a; }
      e=l+64; { int r=e>>3,c=e&7; float a=0.f;
        for (int k=0;k<8;k++) a+=Vv[r*8+k]*Xs[k*8+c]; kv1=a; Km[e]=a; } }
    __syncthreads();
    // G = A - K*CA ; W = P - K*V^T (in place over Pp) ; Bf = B - K*CB ; emit
    { float gv[4];
#pragma unroll
      for (int j=0;j<4;j++){ int c=4*g4+j;
        float a=As[r4*16+c], w=Pp[r4*16+c];
        for (int k=0;k<8;k++){ a -= Km[r4*8+k]*CA[k*16+c]; w -= Km[r4*8+k]*Vv[c*8+k]; }
        gv[j]=a; Gm[r4*16+c]=a; Pp[r4*16+c]=w; }
      bfv = Bs[l];
      for (int k=0;k<8;k++) bfv -= Km[r4*8+k]*CB[k*4+g4];
      float* dst = ws + EX_OFF + s*448;
      *reinterpret_cast<float4*>(dst + r4*16 + g4*4) =
          make_float4(gv[0],gv[1],gv[2],gv[3]);
      dst[256+l]=kv0; dst[256+64+l]=kv1; dst[384+l]=bfv;
    }
    __syncthreads();
    // T1 = A * W
#pragma unroll
    for (int j=0;j<4;j++){ int c=4*g4+j; float a=0.f;
      for (int k=0;k<16;k++) a+=As[r4*16+k]*Pp[k*16+c]; T1[r4*16+c]=a; }
    __syncthreads();
    // P_pri' = T1 * A^T + Q
#pragma unroll
    for (int j=0;j<4;j++){ int c=4*g4+j; float a=Qs[r4*16+c];
      for (int k=0;k<16;k++) a+=T1[r4*16+k]*As[c*16+k]; Pp[r4*16+c]=a; }
    __syncthreads();
  }
  // steady mats = last step's (converged)
  { float* dst = ws + ST_OFF;
    *reinterpret_cast<float4*>(dst + r4*16 + g4*4) =
        *reinterpret_cast<float4*>(&Gm[r4*16 + g4*4]);
    dst[256+l]=kv0; dst[256+64+l]=kv1; dst[384+l]=bfv; }
}

// ---------------------------------------------------------- phase mat load
__device__ __forceinline__ void ld_rows(const float* __restrict__ m, int q,
    float gm[4][16], float km[4][8], float bf[4][4]) {
#pragma unroll
  for (int r=0;r<4;r++){
    const int row = 4*q + r;
    const float4* gp = reinterpret_cast<const float4*>(m + row*16);
#pragma unroll
    for (int kk=0;kk<4;kk++){ float4 t=gp[kk];
      gm[r][4*kk]=t.x; gm[r][4*kk+1]=t.y; gm[r][4*kk+2]=t.z; gm[r][4*kk+3]=t.w; }
    const float4* kp = reinterpret_cast<const float4*>(m + 256 + row*8);
#pragma unroll
    for (int kk=0;kk<2;kk++){ float4 t=kp[kk];
      km[r][4*kk]=t.x; km[r][4*kk+1]=t.y; km[r][4*kk+2]=t.z; km[r][4*kk+3]=t.w; }
    float4 t = *reinterpret_cast<const float4*>(m + 384 + row*4);
    bf[r][0]=t.x; bf[r][1]=t.y; bf[r][2]=t.z; bf[r][3]=t.w;
  }
}

// one recurrence step: x <- G x + K z + Bf u  (R7 body, unchanged)
__device__ __forceinline__ void rec_step(
    float xr[4], const float gm[4][16], const float km[4][8],
    const float bf[4][4], float4 z0, float4 z1, float4 u0)
{
  float xk[16];
  bc4<0>(xr, xk); bc4<1>(xr, xk+4); bc4<2>(xr, xk+8); bc4<3>(xr, xk+12);
  float xn[4];
#pragma unroll
  for (int r=0;r<4;r++){
    float a = bf[r][0]*u0.x + bf[r][1]*u0.y + bf[r][2]*u0.z + bf[r][3]*u0.w;
    a += km[r][0]*z0.x + km[r][1]*z0.y + km[r][2]*z0.z + km[r][3]*z0.w;
    a += km[r][4]*z1.x + km[r][5]*z1.y + km[r][6]*z1.z + km[r][7]*z1.w;
#pragma unroll
    for (int k=0;k<16;k++) a += gm[r][k]*xk[k];
    xn[r]=a;
  }
#pragma unroll
  for (int r=0;r<4;r++) xr[r]=xn[r];
}

// MODE 1: chunk 0 -- exact from x0 (EX gains steps 1..8, then ST).
// MODE 0: chunk j>=1 -- 24 warm-up steps from state 0 at t=s0-24 (steady
//         gains; discarded), then nst real steps writing out.
template<int MODE>
__device__ __forceinline__ void chunk_run(
    const float* __restrict__ obs, const float* __restrict__ inp,
    const float* __restrict__ x0g, const float* __restrict__ ws,
    float* __restrict__ out, int j, int g)
{
  const int l=threadIdx.x, bl=l>>2, q=l&3, b=g*16+bl;
  const int s0 = j*LCH;
  const int nst = (NSTEP - s0 < LCH) ? (NSTEP - s0) : LCH;

  float gm[4][16], km[4][8], bf[4][4];
  if (MODE==1) ld_rows(ws + EX_OFF, q, gm, km, bf);
  else         ld_rows(ws + ST_OFF, q, gm, km, bf);

  float xr[4];
  if (MODE==0){ xr[0]=xr[1]=xr[2]=xr[3]=0.f; }
  else {
    float4 x = *reinterpret_cast<const float4*>(x0g + q*4);
    xr[0]=x.x; xr[1]=x.y; xr[2]=x.z; xr[3]=x.w;
    *reinterpret_cast<float4*>(out + (size_t)b*(SEQ_T*16) + q*4) = x;  // t=0
  }

  const float* zp = obs + (size_t)b*(SEQ_T*8);
  const float* up = inp + (size_t)b*(SEQ_T*4);

  if (MODE==0){
    // ---- warm-up: steps consume t = s0-WUP+1 .. s0 (state discarded).
    // t range [9, 4064]: no clamp needed. Depth-2 named rotation (R7).
    const int t0 = s0 - WUP;
    float4 z0a = *reinterpret_cast<const float4*>(zp + (size_t)(t0+1)*8);
    float4 z1a = *reinterpret_cast<const float4*>(zp + (size_t)(t0+1)*8 + 4);
    float4 u0a = *reinterpret_cast<const float4*>(up + (size_t)(t0+1)*4);
    float4 z0b = *reinterpret_cast<const float4*>(zp + (size_t)(t0+2)*8);
    float4 z1b = *reinterpret_cast<const float4*>(zp + (size_t)(t0+2)*8 + 4);
    float4 u0b = *reinterpret_cast<const float4*>(up + (size_t)(t0+2)*4);
    for (int st=0; st<WUP; st++){
      float4 z0=z0a, z1=z1a, u0=u0a;
      z0a=z0b; z1a=z1b; u0a=u0b;
      { const size_t t = (size_t)(t0+st+3);   // <= s0+2 <= 4066, in-bounds
        z0b = *reinterpret_cast<const float4*>(zp + t*8);
        z1b = *reinterpret_cast<const float4*>(zp + t*8 + 4);
        u0b = *reinterpret_cast<const float4*>(up + t*4);
      }
      rec_step(xr, gm, km, bf, z0, z1, u0);
    }
  }

  // ---- main: steps consume t = s0+1 .. s0+nst, write x_t.
  float4 z0a = *reinterpret_cast<const float4*>(zp + (size_t)(s0+1)*8);
  float4 z1a = *reinterpret_cast<const float4*>(zp + (size_t)(s0+1)*8 + 4);
  float4 u0a = *reinterpret_cast<const float4*>(up + (size_t)(s0+1)*4);
  float4 z0b = *reinterpret_cast<const float4*>(zp + (size_t)(s0+2)*8);
  float4 z1b = *reinterpret_cast<const float4*>(zp + (size_t)(s0+2)*8 + 4);
  float4 u0b = *reinterpret_cast<const float4*>(up + (size_t)(s0+2)*4);

  for (int st=0; st<nst; st++){
    float4 z0=z0a, z1=z1a, u0=u0a;
    z0a=z0b; z1a=z1b; u0a=u0b;
    { int tn = s0+st+3; tn = (tn > NSTEP) ? NSTEP : tn;   // branch-free clamp
      const size_t t = (size_t)tn;
      z0b = *reinterpret_cast<const float4*>(zp + t*8);
      z1b = *reinterpret_cast<const float4*>(zp + t*8 + 4);
      u0b = *reinterpret_cast<const float4*>(up + t*4);
    }
    rec_step(xr, gm, km, bf, z0, z1, u0);
    *reinterpret_cast<float4*>(out + (size_t)b*(SEQ_T*16) +
                               (size_t)(s0+st+1)*16 + q*4) =
        make_float4(xr[0],xr[1],xr[2],xr[3]);
    if (MODE==1 && st+1 < nst){
      if (st+1 < NEX)       ld_rows(ws + EX_OFF + (st+1)*448, q, gm, km, bf);
      else if (st+1 == NEX) ld_rows(ws + ST_OFF, q, gm, km, bf);
    }
  }
}

__global__ __launch_bounds__(64,2) void k_chunk(
    const float* __restrict__ obs, const float* __restrict__ inp,
    const float* __restrict__ x0g, const float* __restrict__ ws,
    float* __restrict__ out)
{
  const int j = blockIdx.x>>4, g = blockIdx.x&15;
  if (j==0) chunk_run<1>(obs, inp, x0g, ws, out, j, g);
  else      chunk_run<0>(obs, inp, x0g, ws, out, j, g);
}

// ------------------------------------------------------------- launcher
extern "C" void kernel_launch(void* const* d_in, const int* in_sizes, int n_in,
                              void* d_out, int out_size, void* d_ws, size_t ws_size,
                              hipStream_t stream) {
  const float* obs = (const float*)d_in[0];
  const float* inp = (const float*)d_in[1];
  const float* A   = (const float*)d_in[2];
  const float* B   = (const float*)d_in[3];
  const float* C   = (const float*)d_in[4];
  const float* Q   = (const float*)d_in[5];
  const float* R   = (const float*)d_in[6];
  const float* x0  = (const float*)d_in[7];
  float* out = (float*)d_out;
  float* ws  = (float*)d_ws;

  k_riccati<<<dim3(1),       dim3(64), 0, stream>>>(A, B, C, Q, R, ws);
  k_chunk  <<<dim3(NCHT*16), dim3(64), 0, stream>>>(obs, inp, x0, ws, out);
}

// Round 17
// 161.284 us; speedup vs baseline: 2.0025x; 1.0247x over previous
//
#include <hip/hip_runtime.h>

// Kalman filter, BATCH=256, SEQ=4096, N=16, M=8, U=4.
// STRUCTURE (R14 WIN, 196.5 -> 165.3us): warm-up replaces the parallel
// scan. G = (I-KC)A has rho ~ 0.45 (Riccati contraction ~0.2 = rho^2);
// state information older than WUP steps is numerically irrelevant vs the
// 7.8e-3 tolerance. Each chunk j>=1 starts from state 0 at t = s0-WUP
// (discarded warm-up steps, steady gains), then its 32 real steps.
// Chunk 0 exact from x0 (EX gains first 8). Two kernels total.
// R15..R17: WUP 24 -> 16. G^16 ~ 3e-6 -- still ~1000x under tolerance;
// k_chunk wall scales with serial steps/wave: 48/56 = 0.857 -> ~52us (the
// ~2.5k cy/step wall is memory-system-set; 6 falsified micro-variants
// (R3/R7/R9/R10/R11/R13) say source-level scheduling can't move it --
// only step-count can).
// (R17 == R15 resubmitted: R15/R16 hit GPU-acquisition timeouts, never ran.)
// Inner loop: R7 body (branch-free depth-2 named rotation, single basic
// block) -- proven neutral-best; do not touch.

#define SEQ_T  4096
#define NSTEP  4095
#define NB     256
#define NEX    8
#define LCH    32
#define NCHT   128   // chunks 0..127; chunk j covers steps j*32 .. j*32+31 (<4095)
#define WUP    16    // warm-up steps; G^16 ~ 3e-6 (rho ~ 0.45)

// workspace layout (float offsets): EX gains (8 steps x 448) + ST gains.
#define EX_OFF 0
#define ST_OFF (NEX*448)
// total = 8*448 + 448 = 4032+448 floats (~18 KB)

// ---------------------------------------------------------------- DPP util
template<int KQ>
__device__ __forceinline__ void bc4(const float* xr, float* xk) {
#pragma unroll
  for (int r = 0; r < 4; r++)
    xk[r] = __int_as_float(__builtin_amdgcn_update_dpp(
        0, __float_as_int(xr[r]), KQ * 0x55, 0xF, 0xF, true));
}

// ---------------------------------------------------------------- k_riccati
__global__ __launch_bounds__(64) void k_riccati(
    const float* __restrict__ Ag, const float* __restrict__ Bg,
    const float* __restrict__ Cg, const float* __restrict__ Qg,
    const float* __restrict__ Rg, float* __restrict__ ws)
{
  const int l = threadIdx.x;
  __shared__ float As[256], Qs[256], Cs[128], Bs[64], CA[128], CB[32];
  __shared__ float Pp[256], Vv[128], Km[128], Gm[256], T1[256], Xs[64];

#pragma unroll
  for (int j=0;j<4;j++){ int e=l+64*j; As[e]=Ag[e]; Qs[e]=Qg[e]; }
  Cs[l]=Cg[l]; Cs[l+64]=Cg[l+64];
  Bs[l]=Bg[l];
  const float rr = Rg[l];
  __syncthreads();

  const int r4=l>>2, g4=l&3;   // (row, col-group) for 16x16 work
  const int r8=l>>3, c8=l&7;   // (row, col) for 8-wide work

  // CA = C*A (8x16), CB = C*B (8x4), Pp0 = A*A^T + Q
  { int e=l; { int r=e>>4,c=e&15; float a=0.f;
      for (int k=0;k<16;k++) a+=Cs[r*16+k]*As[k*16+c]; CA[e]=a; }
    e=l+64; { int r=e>>4,c=e&15; float a=0.f;
      for (int k=0;k<16;k++) a+=Cs[r*16+k]*As[k*16+c]; CA[e]=a; }
    if (l<32){ int r=l>>2,c=l&3; float a=0.f;
      for (int k=0;k<16;k++) a+=Cs[r*16+k]*Bs[k*4+c]; CB[l]=a; }
#pragma unroll
    for (int j=0;j<4;j++){ int c=4*g4+j; float a=Qs[r4*16+c];
      for (int k=0;k<16;k++) a+=As[r4*16+k]*As[c*16+k]; Pp[r4*16+c]=a; }
  }
  __syncthreads();

  float kv0=0.f, kv1=0.f, bfv=0.f;
  for (int s=0;s<NEX;s++){
    // V = P_pri * C^T (16x8), 2 elems/lane
    { int e=l; { int r=e>>3,c=e&7; float a=0.f;
        for (int k=0;k<16;k++) a+=Pp[r*16+k]*Cs[c*16+k]; Vv[e]=a; }
      e=l+64; { int r=e>>3,c=e&7; float a=0.f;
        for (int k=0;k<16;k++) a+=Pp[r*16+k]*Cs[c*16+k]; Vv[e]=a; } }
    __syncthreads();
    // S = C*V + R, then in-register Gauss-Jordan via shfl (no barriers)
    { float sv=rr;
      for (int k=0;k<16;k++) sv += Cs[r8*16+k]*Vv[k*8+c8];
      float xv = (r8==c8)?1.f:0.f;
#pragma unroll
      for (int p=0;p<8;p++){
        float spp = __shfl(sv, p*9);
        float pr  = 1.0f/spp;
        float spc = __shfl(sv, p*8+c8);
        float xpc = __shfl(xv, p*8+c8);
        float srp = __shfl(sv, r8*8+p);
        float f = srp*pr;
        if (r8==p){ sv = spc*pr; xv = xpc*pr; }
        else      { sv -= f*spc; xv -= f*xpc; }
      }
      Xs[l]=xv; }
    __syncthreads();
    // K = V * S^-1 (16x8), 2 elems/lane; keep in regs for emit
    { int e=l; { int r=e>>3,c=e&7; float a=0.f;
        for (int k=0;k<8;k++) a+=Vv[r*8+k]*Xs[k*8+c]; kv0=a; Km[e]=a; }
      e=l+64; { int r=e>>3,c=e&7; float a=0.f;
        for (int k=0;k<8;k++) a+=Vv[r*8+k]*Xs[k*8+c]; kv1=a; Km[e]=a; } }
    __syncthreads();
    // G = A - K*CA ; W = P - K*V^T (in place over Pp) ; Bf = B - K*CB ; emit
    { float gv[4];
#pragma unroll
      for (int j=0;j<4;j++){ int c=4*g4+j;
        float a=As[r4*16+c], w=Pp[r4*16+c];
        for (int k=0;k<8;k++){ a -= Km[r4*8+k]*CA[k*16+c]; w -= Km[r4*8+k]*Vv[c*8+k]; }
        gv[j]=a; Gm[r4*16+c]=a; Pp[r4*16+c]=w; }
      bfv = Bs[l];
      for (int k=0;k<8;k++) bfv -= Km[r4*8+k]*CB[k*4+g4];
      float* dst = ws + EX_OFF + s*448;
      *reinterpret_cast<float4*>(dst + r4*16 + g4*4) =
          make_float4(gv[0],gv[1],gv[2],gv[3]);
      dst[256+l]=kv0; dst[256+64+l]=kv1; dst[384+l]=bfv;
    }
    __syncthreads();
    // T1 = A * W
#pragma unroll
    for (int j=0;j<4;j++){ int c=4*g4+j; float a=0.f;
      for (int k=0;k<16;k++) a+=As[r4*16+k]*Pp[k*16+c]; T1[r4*16+c]=a; }
    __syncthreads();
    // P_pri' = T1 * A^T + Q
#pragma unroll
    for (int j=0;j<4;j++){ int c=4*g4+j; float a=Qs[r4*16+c];
      for (int k=0;k<16;k++) a+=T1[r4*16+k]*As[c*16+k]; Pp[r4*16+c]=a; }
    __syncthreads();
  }
  // steady mats = last step's (converged)
  { float* dst = ws + ST_OFF;
    *reinterpret_cast<float4*>(dst + r4*16 + g4*4) =
        *reinterpret_cast<float4*>(&Gm[r4*16 + g4*4]);
    dst[256+l]=kv0; dst[256+64+l]=kv1; dst[384+l]=bfv; }
}

// ---------------------------------------------------------- phase mat load
__device__ __forceinline__ void ld_rows(const float* __restrict__ m, int q,
    float gm[4][16], float km[4][8], float bf[4][4]) {
#pragma unroll
  for (int r=0;r<4;r++){
    const int row = 4*q + r;
    const float4* gp = reinterpret_cast<const float4*>(m + row*16);
#pragma unroll
    for (int kk=0;kk<4;kk++){ float4 t=gp[kk];
      gm[r][4*kk]=t.x; gm[r][4*kk+1]=t.y; gm[r][4*kk+2]=t.z; gm[r][4*kk+3]=t.w; }
    const float4* kp = reinterpret_cast<const float4*>(m + 256 + row*8);
#pragma unroll
    for (int kk=0;kk<2;kk++){ float4 t=kp[kk];
      km[r][4*kk]=t.x; km[r][4*kk+1]=t.y; km[r][4*kk+2]=t.z; km[r][4*kk+3]=t.w; }
    float4 t = *reinterpret_cast<const float4*>(m + 384 + row*4);
    bf[r][0]=t.x; bf[r][1]=t.y; bf[r][2]=t.z; bf[r][3]=t.w;
  }
}

// one recurrence step: x <- G x + K z + Bf u  (R7 body, unchanged)
__device__ __forceinline__ void rec_step(
    float xr[4], const float gm[4][16], const float km[4][8],
    const float bf[4][4], float4 z0, float4 z1, float4 u0)
{
  float xk[16];
  bc4<0>(xr, xk); bc4<1>(xr, xk+4); bc4<2>(xr, xk+8); bc4<3>(xr, xk+12);
  float xn[4];
#pragma unroll
  for (int r=0;r<4;r++){
    float a = bf[r][0]*u0.x + bf[r][1]*u0.y + bf[r][2]*u0.z + bf[r][3]*u0.w;
    a += km[r][0]*z0.x + km[r][1]*z0.y + km[r][2]*z0.z + km[r][3]*z0.w;
    a += km[r][4]*z1.x + km[r][5]*z1.y + km[r][6]*z1.z + km[r][7]*z1.w;
#pragma unroll
    for (int k=0;k<16;k++) a += gm[r][k]*xk[k];
    xn[r]=a;
  }
#pragma unroll
  for (int r=0;r<4;r++) xr[r]=xn[r];
}

// MODE 1: chunk 0 -- exact from x0 (EX gains steps 1..8, then ST).
// MODE 0: chunk j>=1 -- WUP warm-up steps from state 0 at t=s0-WUP (steady
//         gains; discarded), then nst real steps writing out.
template<int MODE>
__device__ __forceinline__ void chunk_run(
    const float* __restrict__ obs, const float* __restrict__ inp,
    const float* __restrict__ x0g, const float* __restrict__ ws,
    float* __restrict__ out, int j, int g)
{
  const int l=threadIdx.x, bl=l>>2, q=l&3, b=g*16+bl;
  const int s0 = j*LCH;
  const int nst = (NSTEP - s0 < LCH) ? (NSTEP - s0) : LCH;

  float gm[4][16], km[4][8], bf[4][4];
  if (MODE==1) ld_rows(ws + EX_OFF, q, gm, km, bf);
  else         ld_rows(ws + ST_OFF, q, gm, km, bf);

  float xr[4];
  if (MODE==0){ xr[0]=xr[1]=xr[2]=xr[3]=0.f; }
  else {
    float4 x = *reinterpret_cast<const float4*>(x0g + q*4);
    xr[0]=x.x; xr[1]=x.y; xr[2]=x.z; xr[3]=x.w;
    *reinterpret_cast<float4*>(out + (size_t)b*(SEQ_T*16) + q*4) = x;  // t=0
  }

  const float* zp = obs + (size_t)b*(SEQ_T*8);
  const float* up = inp + (size_t)b*(SEQ_T*4);

  if (MODE==0){
    // ---- warm-up: steps consume t = s0-WUP+1 .. s0 (state discarded).
    // t range [17, 4064]: no clamp needed. Depth-2 named rotation (R7).
    const int t0 = s0 - WUP;
    float4 z0a = *reinterpret_cast<const float4*>(zp + (size_t)(t0+1)*8);
    float4 z1a = *reinterpret_cast<const float4*>(zp + (size_t)(t0+1)*8 + 4);
    float4 u0a = *reinterpret_cast<const float4*>(up + (size_t)(t0+1)*4);
    float4 z0b = *reinterpret_cast<const float4*>(zp + (size_t)(t0+2)*8);
    float4 z1b = *reinterpret_cast<const float4*>(zp + (size_t)(t0+2)*8 + 4);
    float4 u0b = *reinterpret_cast<const float4*>(up + (size_t)(t0+2)*4);
    for (int st=0; st<WUP; st++){
      float4 z0=z0a, z1=z1a, u0=u0a;
      z0a=z0b; z1a=z1b; u0a=u0b;
      { const size_t t = (size_t)(t0+st+3);   // <= s0+2 <= 4066, in-bounds
        z0b = *reinterpret_cast<const float4*>(zp + t*8);
        z1b = *reinterpret_cast<const float4*>(zp + t*8 + 4);
        u0b = *reinterpret_cast<const float4*>(up + t*4);
      }
      rec_step(xr, gm, km, bf, z0, z1, u0);
    }
  }

  // ---- main: steps consume t = s0+1 .. s0+nst, write x_t.
  float4 z0a = *reinterpret_cast<const float4*>(zp + (size_t)(s0+1)*8);
  float4 z1a = *reinterpret_cast<const float4*>(zp + (size_t)(s0+1)*8 + 4);
  float4 u0a = *reinterpret_cast<const float4*>(up + (size_t)(s0+1)*4);
  float4 z0b = *reinterpret_cast<const float4*>(zp + (size_t)(s0+2)*8);
  float4 z1b = *reinterpret_cast<const float4*>(zp + (size_t)(s0+2)*8 + 4);
  float4 u0b = *reinterpret_cast<const float4*>(up + (size_t)(s0+2)*4);

  for (int st=0; st<nst; st++){
    float4 z0=z0a, z1=z1a, u0=u0a;
    z0a=z0b; z1a=z1b; u0a=u0b;
    { int tn = s0+st+3; tn = (tn > NSTEP) ? NSTEP : tn;   // branch-free clamp
      const size_t t = (size_t)tn;
      z0b = *reinterpret_cast<const float4*>(zp + t*8);
      z1b = *reinterpret_cast<const float4*>(zp + t*8 + 4);
      u0b = *reinterpret_cast<const float4*>(up + t*4);
    }
    rec_step(xr, gm, km, bf, z0, z1, u0);
    *reinterpret_cast<float4*>(out + (size_t)b*(SEQ_T*16) +
                               (size_t)(s0+st+1)*16 + q*4) =
        make_float4(xr[0],xr[1],xr[2],xr[3]);
    if (MODE==1 && st+1 < nst){
      if (st+1 < NEX)       ld_rows(ws + EX_OFF + (st+1)*448, q, gm, km, bf);
      else if (st+1 == NEX) ld_rows(ws + ST_OFF, q, gm, km, bf);
    }
  }
}

__global__ __launch_bounds__(64,2) void k_chunk(
    const float* __restrict__ obs, const float* __restrict__ inp,
    const float* __restrict__ x0g, const float* __restrict__ ws,
    float* __restrict__ out)
{
  const int j = blockIdx.x>>4, g = blockIdx.x&15;
  if (j==0) chunk_run<1>(obs, inp, x0g, ws, out, j, g);
  else      chunk_run<0>(obs, inp, x0g, ws, out, j, g);
}

// ------------------------------------------------------------- launcher
extern "C" void kernel_launch(void* const* d_in, const int* in_sizes, int n_in,
                              void* d_out, int out_size, void* d_ws, size_t ws_size,
                              hipStream_t stream) {
  const float* obs = (const float*)d_in[0];
  const float* inp = (const float*)d_in[1];
  const float* A   = (const float*)d_in[2];
  const float* B   = (const float*)d_in[3];
  const float* C   = (const float*)d_in[4];
  const float* Q   = (const float*)d_in[5];
  const float* R   = (const float*)d_in[6];
  const float* x0  = (const float*)d_in[7];
  float* out = (float*)d_out;
  float* ws  = (float*)d_ws;

  k_riccati<<<dim3(1),       dim3(64), 0, stream>>>(A, B, C, Q, R, ws);
  k_chunk  <<<dim3(NCHT*16), dim3(64), 0, stream>>>(obs, inp, x0, ws, out);
}